// Round 14
// baseline (2014.923 us; speedup 1.0000x reference)
//
#include <hip/hip_runtime.h>
#include <hip/hip_bf16.h>
#include <math.h>

#define S_LEN 256
#define B 32
#define E 512
#define H 512
#define G4 2048          // 4*H
#define T_TAGS 30
#define START_TAG 28
#define STOP_TAG 29

typedef unsigned short u16;
typedef unsigned int   u32;
typedef unsigned long long u64;
typedef __attribute__((ext_vector_type(8))) short bf16x8;
typedef __attribute__((ext_vector_type(4))) float f32x4;

__device__ __forceinline__ float bf2f(u16 u){
  u32 x = ((u32)u) << 16;
  return __uint_as_float(x);
}
__device__ __forceinline__ u16 f2bf(float f){
  u32 x = __float_as_uint(f);
  u32 r = (x + 0x7fffu + ((x >> 16) & 1u)) >> 16;
  return (u16)r;
}
__device__ __forceinline__ float sigf(float x){
  return 1.0f / (1.0f + __expf(-x));
}
__device__ __forceinline__ float tanh_fast(float x){
  return 1.0f - 2.0f / (__expf(2.0f * x) + 1.0f);
}

// ---------------- prep: gather + f32->bf16 for A (emb rows) ----------------
__global__ __launch_bounds__(256) void k_prep_a(
    const int* __restrict__ sent, const float* __restrict__ emb,
    u16* __restrict__ a16)
{
  int g = (blockIdx.x * 256 + threadIdx.x) * 8;      // < 8192*512
  int token = g >> 9, k = g & 511;
  const float* src = emb + (size_t)sent[token] * E + k;
  float4 v0 = *reinterpret_cast<const float4*>(src);
  float4 v1 = *reinterpret_cast<const float4*>(src + 4);
  u16 o[8];
  o[0]=f2bf(v0.x); o[1]=f2bf(v0.y); o[2]=f2bf(v0.z); o[3]=f2bf(v0.w);
  o[4]=f2bf(v1.x); o[5]=f2bf(v1.y); o[6]=f2bf(v1.z); o[7]=f2bf(v1.w);
  *reinterpret_cast<uint4*>(a16 + g) = *reinterpret_cast<const uint4*>(o);
}

// ---------------- init: h0 -> bf16 parity0, zero barrier flags ----------------
__global__ __launch_bounds__(256) void k_init16(
    const float* __restrict__ h0, u16* __restrict__ h16, u32* __restrict__ bar)
{
  int g = (blockIdx.x * 256 + threadIdx.x) * 8;      // < 2*B*H = 32768
  float4 v0 = *reinterpret_cast<const float4*>(h0 + g);
  float4 v1 = *reinterpret_cast<const float4*>(h0 + g + 4);
  u16 o[8];
  o[0]=f2bf(v0.x); o[1]=f2bf(v0.y); o[2]=f2bf(v0.z); o[3]=f2bf(v0.w);
  o[4]=f2bf(v1.x); o[5]=f2bf(v1.y); o[6]=f2bf(v1.z); o[7]=f2bf(v1.w);
  *reinterpret_cast<uint4*>(h16 + g) = *reinterpret_cast<const uint4*>(o);
  if (blockIdx.x == 0 && threadIdx.x < 64) bar[threadIdx.x] = 0u;
}

// ---------------- xw MFMA helper: 4 gate accs over full K from a16 row ----------------
__device__ __forceinline__ void compute_xw(
    const u64* __restrict__ ap, const u16* __restrict__ wih_s,
    const int* __restrict__ bbase, int sw, f32x4* __restrict__ xacc)
{
  u64 qb[32];
  #pragma unroll
  for (int kt = 0; kt < 16; ++kt){
    qb[2*kt]   = ap[kt * 8];
    qb[2*kt+1] = ap[kt * 8 + 1];
  }
  #pragma unroll
  for (int G = 0; G < 4; ++G) xacc[G] = (f32x4){0.f, 0.f, 0.f, 0.f};
  #pragma unroll
  for (int kt = 0; kt < 16; ++kt){
    union { u64 q[2]; bf16x8 v; } ua;
    ua.q[0] = qb[2*kt]; ua.q[1] = qb[2*kt+1];
    #pragma unroll
    for (int G = 0; G < 4; ++G){
      bf16x8 bfr = *reinterpret_cast<const bf16x8*>(&wih_s[(bbase[G] + (kt << 5)) ^ sw]);
      xacc[G] = __builtin_amdgcn_mfma_f32_16x16x32_bf16(ua.v, bfr, xacc[G], 0, 0, 0);
    }
  }
}

// ---------------- persistent fused BiLSTM: recurrence + in-kernel xw GEMM ----------------
// 64 blocks x 128 threads (2 waves). dir = bx>>5, slice = bx&31, j0 = slice*16.
// W_hh AND W_ih slices resident in LDS (128 KB). Wave wr owns batches
// [wr*16,wr*16+16) full-K -> all 4 gates of (batch,j) in one lane (in-register
// epilogue). Per step: poll flags -> sc1 h load -> hh-MFMA accumulated ONTO the
// prefetched xw accumulator -> epilogue(+bias) -> publish -> compute xw(t+1)
// (independent of h; hides flag propagation latency). r13 flag protocol.
__global__ __launch_bounds__(128) void k_lstm_fused(
    const float* __restrict__ w_hh_f, const float* __restrict__ w_hh_b,
    const float* __restrict__ w_ih_f, const float* __restrict__ w_ih_b,
    const float* __restrict__ b_ih_f, const float* __restrict__ b_hh_f,
    const float* __restrict__ b_ih_b, const float* __restrict__ b_hh_b,
    const u16* __restrict__ a16,      // [8192][512] bf16 (token-major, s*B+b)
    u16* __restrict__ ht,             // [2 parity][2 dir][32][512] bf16
    const float* __restrict__ c0,     // [2][32][512] f32
    u16* __restrict__ hseq,           // [2 dir][8192][512] bf16
    u32* __restrict__ bar)            // [2 dir][32] flags (zeroed each launch)
{
  __shared__ u16 whh_s[64 * 512];     // 64 KB, XOR-swizzled
  __shared__ u16 wih_s[64 * 512];     // 64 KB, XOR-swizzled

  const int bx    = blockIdx.x;
  const int dir   = bx >> 5;
  const int slice = bx & 31;
  const int j0    = slice << 4;
  const int tid   = threadIdx.x;      // 0..127
  const int l     = tid & 63;
  const int wr    = tid >> 6;         // wave = batch half
  const int lr    = l & 15, lh = l >> 4;
  const int sw    = (lr & 7) << 3;

  // ---- stage W_hh and W_ih slices (f32 -> bf16) into LDS once ----
  {
    const float* hsrc = dir ? w_hh_b : w_hh_f;
    const float* isrc = dir ? w_ih_b : w_ih_f;
    #pragma unroll
    for (int i = 0; i < 32; ++i){
      int u = i * 128 + tid;            // 0..4095 (8-f32 units)
      int r = u >> 6, ku8 = u & 63;
      int g = r >> 4, jj = r & 15;
      size_t roff = (size_t)((g << 9) + j0 + jj) * H + ku8 * 8;
      int idx = (r * 512 + ku8 * 8) ^ ((r & 7) << 3);
      {
        float4 a = *reinterpret_cast<const float4*>(hsrc + roff);
        float4 b = *reinterpret_cast<const float4*>(hsrc + roff + 4);
        u16 o[8];
        o[0]=f2bf(a.x); o[1]=f2bf(a.y); o[2]=f2bf(a.z); o[3]=f2bf(a.w);
        o[4]=f2bf(b.x); o[5]=f2bf(b.y); o[6]=f2bf(b.z); o[7]=f2bf(b.w);
        *reinterpret_cast<uint4*>(&whh_s[idx]) = *reinterpret_cast<const uint4*>(o);
      }
      {
        float4 a = *reinterpret_cast<const float4*>(isrc + roff);
        float4 b = *reinterpret_cast<const float4*>(isrc + roff + 4);
        u16 o[8];
        o[0]=f2bf(a.x); o[1]=f2bf(a.y); o[2]=f2bf(a.z); o[3]=f2bf(a.w);
        o[4]=f2bf(b.x); o[5]=f2bf(b.y); o[6]=f2bf(b.z); o[7]=f2bf(b.w);
        *reinterpret_cast<uint4*>(&wih_s[idx]) = *reinterpret_cast<const uint4*>(o);
      }
    }
  }

  int bbase[4];
  #pragma unroll
  for (int G = 0; G < 4; ++G)
    bbase[G] = (G * 16 + lr) * 512 + (lh << 3);

  // h A-fragment offset (u16): batch row wr*16+lr, k starts lh*8
  const int aoff = ((wr << 4) + lr) * 512 + (lh << 3);

  // per-lane bias (j = j0+lr, per gate; same for all 4 batches this lane owns)
  float bias_g[4];
  {
    const float* bi = dir ? b_ih_b : b_ih_f;
    const float* bh = dir ? b_hh_b : b_hh_f;
    #pragma unroll
    for (int G = 0; G < 4; ++G)
      bias_g[G] = bi[(G << 9) + j0 + lr] + bh[(G << 9) + j0 + lr];
  }

  // epilogue: lane owns (batch = wr*16 + lh*4 + r, j = j0 + lr)
  float c_reg[4];
  #pragma unroll
  for (int r = 0; r < 4; ++r)
    c_reg[r] = c0[((size_t)dir * B + (wr * 16 + lh * 4 + r)) * H + j0 + lr];

  const u32* flg = bar + (dir << 5);
  const int PSTRIDE = 2 * B * H;        // u16 per parity

  __syncthreads();

  // prologue: xw accumulator for step 0
  f32x4 xacc[4];
  {
    int s0 = dir ? (S_LEN - 1) : 0;
    const u64* ap = reinterpret_cast<const u64*>(
        a16 + ((size_t)(s0 * B + wr * 16 + lr)) * 512 + (lh << 3));
    compute_xw(ap, wih_s, bbase, sw, xacc);
  }

  for (int t = 0; t < S_LEN; ++t){
    const int s_eff = dir ? (S_LEN - 1 - t) : t;

    // 1. wave-local poll: all 32 flags >= t
    {
      u32 f;
      do {
        f = __hip_atomic_load(flg + (l & 31), __ATOMIC_RELAXED, __HIP_MEMORY_SCOPE_AGENT);
      } while (__any(f < (u32)t));
    }

    // 2. batch-issue 32 coherent (sc1) u64 h loads
    const u64* hp = reinterpret_cast<const u64*>(
        ht + (size_t)(t & 1) * PSTRIDE + (size_t)dir * (B * H) + aoff);
    u64 qa[32];
    #pragma unroll
    for (int kt = 0; kt < 16; ++kt){
      qa[2*kt]   = __hip_atomic_load(hp + kt * 8,     __ATOMIC_RELAXED, __HIP_MEMORY_SCOPE_AGENT);
      qa[2*kt+1] = __hip_atomic_load(hp + kt * 8 + 1, __ATOMIC_RELAXED, __HIP_MEMORY_SCOPE_AGENT);
    }

    // 3. hh-MFMA accumulated onto the prefetched xw accumulator
    f32x4 acc[4];
    #pragma unroll
    for (int G = 0; G < 4; ++G) acc[G] = xacc[G];
    #pragma unroll
    for (int kt = 0; kt < 16; ++kt){
      union { u64 q[2]; bf16x8 v; } ua;
      ua.q[0] = qa[2*kt]; ua.q[1] = qa[2*kt+1];
      #pragma unroll
      for (int G = 0; G < 4; ++G){
        bf16x8 bfr = *reinterpret_cast<const bf16x8*>(&whh_s[(bbase[G] + (kt << 5)) ^ sw]);
        acc[G] = __builtin_amdgcn_mfma_f32_16x16x32_bf16(ua.v, bfr, acc[G], 0, 0, 0);
      }
    }

    // 4. in-register epilogue (+bias); pair adjacent j via shfl; sc1 publish h(t+1)
    u32 spack[4];
    #pragma unroll
    for (int r = 0; r < 4; ++r){
      float iv = acc[0][r] + bias_g[0];
      float fv = acc[1][r] + bias_g[1];
      float gv = acc[2][r] + bias_g[2];
      float ov = acc[3][r] + bias_g[3];
      float cn = sigf(fv) * c_reg[r] + sigf(iv) * tanh_fast(gv);
      float hv = sigf(ov) * tanh_fast(cn);
      c_reg[r] = cn;
      u32 hu = (u32)f2bf(hv);
      u32 po = (u32)__shfl_xor((int)hu, 1);
      u32 pack = hu | (po << 16);            // valid on even lr
      spack[r] = pack;
      if ((lr & 1) == 0){
        int batch = wr * 16 + lh * 4 + r;
        size_t off = ((size_t)dir * B + batch) * H + j0 + lr;
        __hip_atomic_store(
            reinterpret_cast<u32*>(ht + (size_t)((t + 1) & 1) * PSTRIDE + off),
            pack, __ATOMIC_RELAXED, __HIP_MEMORY_SCOPE_AGENT);
      }
    }

    // 5. drain ht stores, publish flag
    asm volatile("s_waitcnt vmcnt(0)" ::: "memory");
    __syncthreads();
    if (tid == 0)
      __hip_atomic_store(bar + (dir << 5) + slice, (u32)(t + 1),
                         __ATOMIC_RELAXED, __HIP_MEMORY_SCOPE_AGENT);

    // 6. hseq stores off the critical path
    if ((lr & 1) == 0){
      #pragma unroll
      for (int r = 0; r < 4; ++r){
        int batch = wr * 16 + lh * 4 + r;
        *reinterpret_cast<u32*>(
            hseq + ((size_t)dir * 8192 + (size_t)s_eff * B + batch) * H + j0 + lr) = spack[r];
      }
    }

    // 7. compute xw(t+1) — independent of h; hides flag propagation + peer skew
    if (t < S_LEN - 1){
      int s_next = dir ? (S_LEN - 2 - t) : (t + 1);
      const u64* ap = reinterpret_cast<const u64*>(
          a16 + ((size_t)(s_next * B + wr * 16 + lr)) * 512 + (lh << 3));
      compute_xw(ap, wih_s, bbase, sw, xacc);
    }
  }
}

// ---------------- phase C: feats[b][s][t] = [hf;hb] . w_out[t] + b_out[t] ----------------
__global__ __launch_bounds__(256) void k_feats2(
    const u16* __restrict__ hseq, const float* __restrict__ w_out,
    const float* __restrict__ b_out, float* __restrict__ feats)
{
  __shared__ float row[32][1028];
  int blk = blockIdx.x;
  int tid = threadIdx.x;
  const u16* hf16 = hseq;
  const u16* hb16 = hseq + (size_t)8192 * H;

  #pragma unroll
  for (int it = 0; it < 16; ++it){
    int u = it * 256 + tid;
    int flat = u * 8;
    int i = flat >> 10, d = flat & 1023;
    int m = blk * 32 + i;
    const u16* src = (d < 512) ? (hf16 + (size_t)m * H + d) : (hb16 + (size_t)m * H + d - 512);
    uint4 v = *reinterpret_cast<const uint4*>(src);
    float* dst = &row[i][d];
    dst[0] = bf2f((u16)(v.x & 0xffff)); dst[1] = bf2f((u16)(v.x >> 16));
    dst[2] = bf2f((u16)(v.y & 0xffff)); dst[3] = bf2f((u16)(v.y >> 16));
    dst[4] = bf2f((u16)(v.z & 0xffff)); dst[5] = bf2f((u16)(v.z >> 16));
    dst[6] = bf2f((u16)(v.w & 0xffff)); dst[7] = bf2f((u16)(v.w >> 16));
  }
  __syncthreads();

  int i = tid >> 3, tg = tid & 7;
  const float* w0 = w_out + (size_t)((tg + 0  < T_TAGS) ? tg + 0  : 0) * 1024;
  const float* w1 = w_out + (size_t)((tg + 8  < T_TAGS) ? tg + 8  : 0) * 1024;
  const float* w2 = w_out + (size_t)((tg + 16 < T_TAGS) ? tg + 16 : 0) * 1024;
  const float* w3 = w_out + (size_t)((tg + 24 < T_TAGS) ? tg + 24 : 0) * 1024;
  float s0 = 0.f, s1 = 0.f, s2 = 0.f, s3 = 0.f;
  #pragma unroll 4
  for (int k4 = 0; k4 < 256; ++k4){
    float4 rv = *reinterpret_cast<const float4*>(&row[i][k4 * 4]);
    float4 a = *reinterpret_cast<const float4*>(w0 + k4 * 4);
    float4 b = *reinterpret_cast<const float4*>(w1 + k4 * 4);
    float4 c = *reinterpret_cast<const float4*>(w2 + k4 * 4);
    float4 d = *reinterpret_cast<const float4*>(w3 + k4 * 4);
    s0 = fmaf(a.x,rv.x,s0); s0 = fmaf(a.y,rv.y,s0); s0 = fmaf(a.z,rv.z,s0); s0 = fmaf(a.w,rv.w,s0);
    s1 = fmaf(b.x,rv.x,s1); s1 = fmaf(b.y,rv.y,s1); s1 = fmaf(b.z,rv.z,s1); s1 = fmaf(b.w,rv.w,s1);
    s2 = fmaf(c.x,rv.x,s2); s2 = fmaf(c.y,rv.y,s2); s2 = fmaf(c.z,rv.z,s2); s2 = fmaf(c.w,rv.w,s2);
    s3 = fmaf(d.x,rv.x,s3); s3 = fmaf(d.y,rv.y,s3); s3 = fmaf(d.z,rv.z,s3); s3 = fmaf(d.w,rv.w,s3);
  }
  int m = blk * 32 + i;
  int s = m >> 5, bb = m & 31;
  float* fp = feats + ((size_t)bb * S_LEN + s) * T_TAGS;
  float sums[4] = {s0, s1, s2, s3};
  #pragma unroll
  for (int q = 0; q < 4; ++q){
    int tt = tg + q * 8;
    if (tt < T_TAGS) fp[tt] = sums[q] + b_out[tt];
  }
}

// ---------------- phase D: CRF, one wave per batch element, register-resident ----------------
__global__ __launch_bounds__(64) void k_crf2(
    const float* __restrict__ feats, const float* __restrict__ trans,
    const int* __restrict__ tags, float* __restrict__ scores)
{
  int b = blockIdx.x;
  int l = threadIdx.x;

  float trr[T_TAGS];
  #pragma unroll
  for (int j = 0; j < T_TAGS; ++j)
    trr[j] = (l < T_TAGS) ? trans[l * T_TAGS + j] : -1e30f;

  float fv = (l == START_TAG) ? 0.f : -10000.f;
  const float* fb = feats + (size_t)b * S_LEN * T_TAGS;

  for (int s = 0; s < S_LEN; ++s){
    float feat = (l < T_TAGS) ? fb[s * T_TAGS + l] : 0.f;
    float v[T_TAGS];
    float m = -1e30f;
    #pragma unroll
    for (int j = 0; j < T_TAGS; ++j){
      float fvj = __shfl(fv, j);
      v[j] = fvj + trr[j];
      m = fmaxf(m, v[j]);
    }
    float sum = 0.f;
    #pragma unroll
    for (int j = 0; j < T_TAGS; ++j) sum += __expf(v[j] - m);
    fv = feat + m + __logf(sum);
  }

  float fin = (l < T_TAGS) ? fv + trans[STOP_TAG * T_TAGS + l] : -1e30f;
  float mm = fin;
  #pragma unroll
  for (int o = 32; o > 0; o >>= 1) mm = fmaxf(mm, __shfl_xor(mm, o));
  float e = (l < T_TAGS) ? __expf(fin - mm) : 0.f;
  #pragma unroll
  for (int o = 32; o > 0; o >>= 1) e += __shfl_xor(e, o);
  float fsc = mm + __logf(e);

  float g = 0.f;
  #pragma unroll
  for (int it = 0; it < 4; ++it){
    int s = it * 64 + l;
    int nxt = tags[s * B + b];
    int prv = s ? tags[(s - 1) * B + b] : START_TAG;
    g += trans[nxt * T_TAGS + prv] + fb[s * T_TAGS + nxt];
  }
  #pragma unroll
  for (int o = 32; o > 0; o >>= 1) g += __shfl_down(g, o);
  if (l == 0){
    int last = tags[(S_LEN - 1) * B + b];
    g += trans[STOP_TAG * T_TAGS + last];
    scores[b] = fsc - g;
  }
}

__global__ void k_final(const float* __restrict__ scores, float* __restrict__ out){
  int tid = threadIdx.x;
  float v = (tid < B) ? scores[tid] : 0.f;
  #pragma unroll
  for (int o = 32; o > 0; o >>= 1) v += __shfl_down(v, o);
  if (tid == 0) out[0] = v;
}

// ---------------- host ----------------
extern "C" void kernel_launch(void* const* d_in, const int* in_sizes, int n_in,
                              void* d_out, int out_size, void* d_ws, size_t ws_size,
                              hipStream_t stream)
{
  const int*   sent   = (const int*)d_in[0];
  const int*   tags   = (const int*)d_in[1];
  const float* emb    = (const float*)d_in[2];
  const float* w_ih_f = (const float*)d_in[3];
  const float* w_hh_f = (const float*)d_in[4];
  const float* b_ih_f = (const float*)d_in[5];
  const float* b_hh_f = (const float*)d_in[6];
  const float* w_ih_b = (const float*)d_in[7];
  const float* w_hh_b = (const float*)d_in[8];
  const float* b_ih_b = (const float*)d_in[9];
  const float* b_hh_b = (const float*)d_in[10];
  const float* w_out  = (const float*)d_in[11];
  const float* b_out  = (const float*)d_in[12];
  const float* trans  = (const float*)d_in[13];
  const float* h0     = (const float*)d_in[14];
  const float* c0     = (const float*)d_in[15];

  // ws layout (bytes)
  const size_t OFF_A16  = 0;            // bf16 [8192][512]     = 8 MiB
  const size_t OFF_HSEQ = 8388608;      // bf16 [2][8192][512]  = 16 MiB
  const size_t OFF_HT   = 25165824;     // bf16 [2 parity][2][32][512] = 128 KiB
  const size_t OFF_FEATS= 25296896;     // f32  [32][256][30]   = 960 KiB
  const size_t OFF_SC   = 26279936;     // f32  [32]
  const size_t OFF_BAR  = 26280064;     // u32  [2][32] = 256 B
  const size_t NEED     = 26280320;
  if (ws_size < NEED) return;

  char* ws = (char*)d_ws;
  u16*   a16    = (u16*)(ws + OFF_A16);
  u16*   hseq   = (u16*)(ws + OFF_HSEQ);
  u16*   ht     = (u16*)(ws + OFF_HT);
  float* feats  = (float*)(ws + OFF_FEATS);
  float* scores = (float*)(ws + OFF_SC);
  u32*   bar    = (u32*)(ws + OFF_BAR);

  k_prep_a<<<2048, 256, 0, stream>>>(sent, emb, a16);
  k_init16<<<16, 256, 0, stream>>>(h0, ht, bar);

  k_lstm_fused<<<64, 128, 0, stream>>>(
      w_hh_f, w_hh_b, w_ih_f, w_ih_b,
      b_ih_f, b_hh_f, b_ih_b, b_hh_b,
      a16, ht, c0, hseq, bar);

  k_feats2<<<256, 256, 0, stream>>>(hseq, w_out, b_out, feats);
  k_crf2<<<B, 64, 0, stream>>>(feats, trans, tags, scores);
  k_final<<<1, 64, 0, stream>>>(scores, (float*)d_out);
}

// Round 15
// 1523.305 us; speedup vs baseline: 1.3227x; 1.3227x over previous
//
#include <hip/hip_runtime.h>
#include <hip/hip_bf16.h>
#include <math.h>

#define S_LEN 256
#define B 32
#define E 512
#define H 512
#define G4 2048          // 4*H
#define T_TAGS 30
#define START_TAG 28
#define STOP_TAG 29
#define NWORK 192        // GEMM worker blocks
#define NTILE 2048       // 2 dir x 64 mt x 16 nt

typedef unsigned short u16;
typedef unsigned int   u32;
typedef unsigned long long u64;
typedef __attribute__((ext_vector_type(8))) short bf16x8;
typedef __attribute__((ext_vector_type(4))) float f32x4;

__device__ __forceinline__ float bf2f(u16 u){
  u32 x = ((u32)u) << 16;
  return __uint_as_float(x);
}
__device__ __forceinline__ u16 f2bf(float f){
  u32 x = __float_as_uint(f);
  u32 r = (x + 0x7fffu + ((x >> 16) & 1u)) >> 16;
  return (u16)r;
}
__device__ __forceinline__ float sigf(float x){
  return 1.0f / (1.0f + __expf(-x));
}
__device__ __forceinline__ float tanh_fast(float x){
  return 1.0f - 2.0f / (__expf(2.0f * x) + 1.0f);
}

// ---------------- init: h0 -> bf16 parity0, zero all flags ----------------
__global__ __launch_bounds__(256) void k_init16(
    const float* __restrict__ h0, u16* __restrict__ h16, u32* __restrict__ bar)
{
  int g = (blockIdx.x * 256 + threadIdx.x) * 8;      // < 2*B*H = 32768
  float4 v0 = *reinterpret_cast<const float4*>(h0 + g);
  float4 v1 = *reinterpret_cast<const float4*>(h0 + g + 4);
  u16 o[8];
  o[0]=f2bf(v0.x); o[1]=f2bf(v0.y); o[2]=f2bf(v0.z); o[3]=f2bf(v0.w);
  o[4]=f2bf(v1.x); o[5]=f2bf(v1.y); o[6]=f2bf(v1.z); o[7]=f2bf(v1.w);
  *reinterpret_cast<uint4*>(h16 + g) = *reinterpret_cast<const uint4*>(o);
  if (blockIdx.x == 0 && threadIdx.x < 192) bar[threadIdx.x] = 0u;  // 64 lstm + 128 xw flags
}

// ================= mega kernel: persistent LSTM (blocks 0-63) + xw GEMM workers =================
__global__ __launch_bounds__(256) void k_mega(
    const int* __restrict__ sent, const float* __restrict__ emb,
    const float* __restrict__ w_ih_f, const float* __restrict__ w_ih_b,
    const float* __restrict__ w_hh_f, const float* __restrict__ w_hh_b,
    const float* __restrict__ b_ih_f, const float* __restrict__ b_hh_f,
    const float* __restrict__ b_ih_b, const float* __restrict__ b_hh_b,
    u16* __restrict__ xw,             // [2][8192][2048] bf16 (incl. bias)
    u16* __restrict__ ht,             // [2 parity][2 dir][32][512] bf16
    const float* __restrict__ c0,     // [2][32][512] f32
    u16* __restrict__ hseq,           // [2 dir][8192][512] bf16
    u32* __restrict__ bar)            // [64] lstm flags + [2][64] xw tile flags
{
  __shared__ u16 pool[64 * 512];      // 64 KB (LSTM: w_s; GEMM: As/Bs)
  __shared__ int toks[128];

  const int tid = threadIdx.x;
  u32* lstm_flg = bar;
  u32* xw_flg   = bar + 64;

  if (blockIdx.x < 64){
    // ---------------- LSTM path (r13 k_lstm_fast, xw from concurrent workers) ----------------
    const int bx    = blockIdx.x;
    const int dir   = bx >> 5;
    const int slice = bx & 31;
    const int j0    = slice << 4;
    u16* w_s = pool;

    // stage W_hh slice (f32 -> bf16) into LDS once (all 256 threads)
    {
      const float* wsrc = dir ? w_hh_b : w_hh_f;
      #pragma unroll
      for (int i = 0; i < 16; ++i){
        int u = i * 256 + tid;          // 0..4095 (8-f32 units)
        int r = u >> 6, ku8 = u & 63;
        int g = r >> 4, jj = r & 15;
        const float* src = wsrc + (size_t)((g << 9) + j0 + jj) * H + ku8 * 8;
        float4 a = *reinterpret_cast<const float4*>(src);
        float4 b = *reinterpret_cast<const float4*>(src + 4);
        u16 o[8];
        o[0]=f2bf(a.x); o[1]=f2bf(a.y); o[2]=f2bf(a.z); o[3]=f2bf(a.w);
        o[4]=f2bf(b.x); o[5]=f2bf(b.y); o[6]=f2bf(b.z); o[7]=f2bf(b.w);
        int idx = (r * 512 + ku8 * 8) ^ ((r & 7) << 3);
        *reinterpret_cast<uint4*>(&w_s[idx]) = *reinterpret_cast<const uint4*>(o);
      }
    }

    const int l  = tid & 63;
    const int wv = tid >> 6;            // wave 0..3 (only 0,1 compute)
    const int wr = wv & 1;
    const int lr = l & 15, lh = l >> 4;
    const int sw = (lr & 7) << 3;

    int bbase[4];
    #pragma unroll
    for (int G = 0; G < 4; ++G)
      bbase[G] = (G * 16 + lr) * 512 + (lh << 3);
    const int aoff = ((wr << 4) + lr) * 512 + (lh << 3);

    float c_reg[4];
    if (wv < 2){
      #pragma unroll
      for (int r = 0; r < 4; ++r)
        c_reg[r] = c0[((size_t)dir * B + (wr * 16 + lh * 4 + r)) * H + j0 + lr];
    }

    const u32* flg = lstm_flg + (dir << 5);
    const int PSTRIDE = 2 * B * H;      // u16 per parity
    const u32* xw32 = reinterpret_cast<const u32*>(xw);
    const int lrE = lr & ~1, half = lr & 1;

    __syncthreads();

    // prologue: wait for + load xw(t=0)
    u32 xq[16];
    if (wv < 2){
      int s0 = dir ? (S_LEN - 1) : 0;
      int mt = s0 >> 2;
      u32 f;
      do {
        f = __hip_atomic_load(xw_flg + (dir << 6) + mt, __ATOMIC_RELAXED, __HIP_MEMORY_SCOPE_AGENT);
      } while (__any(f < 16u));
      size_t base = ((size_t)dir * 8192 + (size_t)s0 * B) * G4;
      #pragma unroll
      for (int G = 0; G < 4; ++G)
        #pragma unroll
        for (int r = 0; r < 4; ++r){
          size_t eidx = base + (size_t)(wr * 16 + lh * 4 + r) * G4 + (G << 9) + j0 + lrE;
          xq[G * 4 + r] = __hip_atomic_load(xw32 + (eidx >> 1),
                            __ATOMIC_RELAXED, __HIP_MEMORY_SCOPE_AGENT);
        }
    }
    int mt_ready = dir ? 63 : 0;

    for (int t = 0; t < S_LEN; ++t){
      const int s_eff = dir ? (S_LEN - 1 - t) : t;
      u32 spack[4];

      if (wv < 2){
        // 1. h-flag poll (wave-local, all 32 flags >= t)
        {
          u32 f;
          do {
            f = __hip_atomic_load(flg + (l & 31), __ATOMIC_RELAXED, __HIP_MEMORY_SCOPE_AGENT);
          } while (__any(f < (u32)t));
        }

        // 2. batch-issue 32 coherent (sc1) u64 h loads
        const u64* hp = reinterpret_cast<const u64*>(
            ht + (size_t)(t & 1) * PSTRIDE + (size_t)dir * (B * H) + aoff);
        u64 qa[32];
        #pragma unroll
        for (int kt = 0; kt < 16; ++kt){
          qa[2*kt]   = __hip_atomic_load(hp + kt * 8,     __ATOMIC_RELAXED, __HIP_MEMORY_SCOPE_AGENT);
          qa[2*kt+1] = __hip_atomic_load(hp + kt * 8 + 1, __ATOMIC_RELAXED, __HIP_MEMORY_SCOPE_AGENT);
        }

        // 3. MFMA: 4 gates x full K
        f32x4 acc[4];
        #pragma unroll
        for (int G = 0; G < 4; ++G) acc[G] = (f32x4){0.f, 0.f, 0.f, 0.f};
        #pragma unroll
        for (int kt = 0; kt < 16; ++kt){
          union { u64 q[2]; bf16x8 v; } ua;
          ua.q[0] = qa[2*kt]; ua.q[1] = qa[2*kt+1];
          #pragma unroll
          for (int G = 0; G < 4; ++G){
            bf16x8 bfr = *reinterpret_cast<const bf16x8*>(&w_s[(bbase[G] + (kt << 5)) ^ sw]);
            acc[G] = __builtin_amdgcn_mfma_f32_16x16x32_bf16(ua.v, bfr, acc[G], 0, 0, 0);
          }
        }

        // 4. in-register epilogue (xw includes bias); sc1 publish h(t+1)
        #pragma unroll
        for (int r = 0; r < 4; ++r){
          float iv = acc[0][r] + bf2f((u16)(xq[0*4+r] >> (16*half)));
          float fv = acc[1][r] + bf2f((u16)(xq[1*4+r] >> (16*half)));
          float gv = acc[2][r] + bf2f((u16)(xq[2*4+r] >> (16*half)));
          float ov = acc[3][r] + bf2f((u16)(xq[3*4+r] >> (16*half)));
          float cn = sigf(fv) * c_reg[r] + sigf(iv) * tanh_fast(gv);
          float hv = sigf(ov) * tanh_fast(cn);
          c_reg[r] = cn;
          u32 hu = (u32)f2bf(hv);
          u32 po = (u32)__shfl_xor((int)hu, 1);
          u32 pack = hu | (po << 16);          // valid on even lr
          spack[r] = pack;
          if ((lr & 1) == 0){
            int batch = wr * 16 + lh * 4 + r;
            size_t off = ((size_t)dir * B + batch) * H + j0 + lr;
            __hip_atomic_store(
                reinterpret_cast<u32*>(ht + (size_t)((t + 1) & 1) * PSTRIDE + off),
                pack, __ATOMIC_RELAXED, __HIP_MEMORY_SCOPE_AGENT);
          }
        }
      }

      // 5. drain ht stores, publish lstm flag
      asm volatile("s_waitcnt vmcnt(0)" ::: "memory");
      __syncthreads();
      if (tid == 0)
        __hip_atomic_store(lstm_flg + (dir << 5) + slice, (u32)(t + 1),
                           __ATOMIC_RELAXED, __HIP_MEMORY_SCOPE_AGENT);

      if (wv < 2){
        // 6. hseq stores off the critical path
        if ((lr & 1) == 0){
          #pragma unroll
          for (int r = 0; r < 4; ++r){
            int batch = wr * 16 + lh * 4 + r;
            *reinterpret_cast<u32*>(
                hseq + ((size_t)dir * 8192 + (size_t)s_eff * B + batch) * H + j0 + lr) = spack[r];
          }
        }
        // 7. next-step xw: flag check (only when m-tile changes) + sc1 loads,
        //    all in the shadow of peer flag propagation
        if (t < S_LEN - 1){
          int s_next = dir ? (S_LEN - 2 - t) : (t + 1);
          int mt = s_next >> 2;
          if (mt != mt_ready){
            u32 f;
            do {
              f = __hip_atomic_load(xw_flg + (dir << 6) + mt, __ATOMIC_RELAXED, __HIP_MEMORY_SCOPE_AGENT);
            } while (__any(f < 16u));
            mt_ready = mt;
          }
          size_t base = ((size_t)dir * 8192 + (size_t)s_next * B) * G4;
          #pragma unroll
          for (int G = 0; G < 4; ++G)
            #pragma unroll
            for (int r = 0; r < 4; ++r){
              size_t eidx = base + (size_t)(wr * 16 + lh * 4 + r) * G4 + (G << 9) + j0 + lrE;
              xq[G * 4 + r] = __hip_atomic_load(xw32 + (eidx >> 1),
                                __ATOMIC_RELAXED, __HIP_MEMORY_SCOPE_AGENT);
            }
        }
      }
    }
  } else {
    // ---------------- GEMM worker path: xw tiles, distance-ordered ----------------
    const int worker = blockIdx.x - 64;   // 0..191
    u16* As = pool;
    u16* Bs = pool + 4096;                // 128x32 u16 each

    const int l  = tid & 63;
    const int wid = tid >> 6;
    const int wr = wid >> 1, wc = wid & 1;
    const int lr = l & 15, lh = l >> 4;
    const int swzr = (lh ^ (lr & 3)) << 3;

    for (int idx = worker; idx < NTILE; idx += NWORK){
      const int dir  = idx & 1;
      const int k    = idx >> 1;
      const int mt_o = k >> 4, nt = k & 15;
      const int mt   = dir ? (63 - mt_o) : mt_o;
      const int m0   = mt << 7, n0 = nt << 7;
      const float* Wp = dir ? w_ih_b : w_ih_f;
      const float* bi = dir ? b_ih_b : b_ih_f;
      const float* bh = dir ? b_hh_b : b_hh_f;

      __syncthreads();
      if (tid < 128) toks[tid] = sent[m0 + tid];

      f32x4 acc[4][4];
      #pragma unroll
      for (int i = 0; i < 4; ++i)
        #pragma unroll
        for (int j = 0; j < 4; ++j)
          acc[i][j] = (f32x4){0.f, 0.f, 0.f, 0.f};

      for (int kt = 0; kt < E; kt += 32){
        __syncthreads();
        // stage A (emb gather, f32->bf16) and B (w_ih, f32->bf16)
        #pragma unroll
        for (int it = 0; it < 4; ++it){
          int a = it * 256 + tid;            // 0..1023
          int row = a >> 3, q = a & 7;
          int c = q >> 1, hf = q & 1;
          int idxe = row * 32 + ((c ^ (row & 3)) << 3) + hf * 4;
          {
            const float* src = emb + (size_t)toks[row] * E + kt + q * 4;
            float4 v = *reinterpret_cast<const float4*>(src);
            u16 o[4] = {f2bf(v.x), f2bf(v.y), f2bf(v.z), f2bf(v.w)};
            *reinterpret_cast<u64*>(&As[idxe]) = *reinterpret_cast<const u64*>(o);
          }
          {
            const float* src = Wp + (size_t)(n0 + row) * E + kt + q * 4;
            float4 v = *reinterpret_cast<const float4*>(src);
            u16 o[4] = {f2bf(v.x), f2bf(v.y), f2bf(v.z), f2bf(v.w)};
            *reinterpret_cast<u64*>(&Bs[idxe]) = *reinterpret_cast<const u64*>(o);
          }
        }
        __syncthreads();
        bf16x8 a[4], b[4];
        #pragma unroll
        for (int mi = 0; mi < 4; ++mi)
          a[mi] = *reinterpret_cast<const bf16x8*>(&As[(wr * 64 + mi * 16 + lr) * 32 + swzr]);
        #pragma unroll
        for (int ni = 0; ni < 4; ++ni)
          b[ni] = *reinterpret_cast<const bf16x8*>(&Bs[(wc * 64 + ni * 16 + lr) * 32 + swzr]);
        #pragma unroll
        for (int mi = 0; mi < 4; ++mi)
          #pragma unroll
          for (int ni = 0; ni < 4; ++ni)
            acc[mi][ni] = __builtin_amdgcn_mfma_f32_16x16x32_bf16(a[mi], b[ni], acc[mi][ni], 0, 0, 0);
      }

      // epilogue: +bias, bf16, sc1 u32 pair stores
      #pragma unroll
      for (int ni = 0; ni < 4; ++ni){
        int n = n0 + wc * 64 + ni * 16 + lr;
        float bias = bi[n] + bh[n];
        #pragma unroll
        for (int mi = 0; mi < 4; ++mi){
          #pragma unroll
          for (int r = 0; r < 4; ++r){
            int m = m0 + wr * 64 + mi * 16 + lh * 4 + r;
            u16 val = f2bf(acc[mi][ni][r] + bias);
            u32 po = (u32)__shfl_xor((int)(u32)val, 1);
            if ((lr & 1) == 0){
              u32 pack = (u32)val | (po << 16);
              size_t eidx = ((size_t)dir * 8192 + m) * G4 + n;   // n even
              __hip_atomic_store(reinterpret_cast<u32*>(xw) + (eidx >> 1),
                                 pack, __ATOMIC_RELAXED, __HIP_MEMORY_SCOPE_AGENT);
            }
          }
        }
      }
      asm volatile("s_waitcnt vmcnt(0)" ::: "memory");
      __syncthreads();
      if (tid == 0)
        __hip_atomic_fetch_add(xw_flg + (dir << 6) + mt, 1u,
                               __ATOMIC_RELAXED, __HIP_MEMORY_SCOPE_AGENT);
    }
  }
}

// ---------------- phase C: feats[b][s][t] = [hf;hb] . w_out[t] + b_out[t] ----------------
__global__ __launch_bounds__(256) void k_feats2(
    const u16* __restrict__ hseq, const float* __restrict__ w_out,
    const float* __restrict__ b_out, float* __restrict__ feats)
{
  __shared__ float row[32][1028];
  int blk = blockIdx.x;
  int tid = threadIdx.x;
  const u16* hf16 = hseq;
  const u16* hb16 = hseq + (size_t)8192 * H;

  #pragma unroll
  for (int it = 0; it < 16; ++it){
    int u = it * 256 + tid;
    int flat = u * 8;
    int i = flat >> 10, d = flat & 1023;
    int m = blk * 32 + i;
    const u16* src = (d < 512) ? (hf16 + (size_t)m * H + d) : (hb16 + (size_t)m * H + d - 512);
    uint4 v = *reinterpret_cast<const uint4*>(src);
    float* dst = &row[i][d];
    dst[0] = bf2f((u16)(v.x & 0xffff)); dst[1] = bf2f((u16)(v.x >> 16));
    dst[2] = bf2f((u16)(v.y & 0xffff)); dst[3] = bf2f((u16)(v.y >> 16));
    dst[4] = bf2f((u16)(v.z & 0xffff)); dst[5] = bf2f((u16)(v.z >> 16));
    dst[6] = bf2f((u16)(v.w & 0xffff)); dst[7] = bf2f((u16)(v.w >> 16));
  }
  __syncthreads();

  int i = tid >> 3, tg = tid & 7;
  const float* w0 = w_out + (size_t)((tg + 0  < T_TAGS) ? tg + 0  : 0) * 1024;
  const float* w1 = w_out + (size_t)((tg + 8  < T_TAGS) ? tg + 8  : 0) * 1024;
  const float* w2 = w_out + (size_t)((tg + 16 < T_TAGS) ? tg + 16 : 0) * 1024;
  const float* w3 = w_out + (size_t)((tg + 24 < T_TAGS) ? tg + 24 : 0) * 1024;
  float s0 = 0.f, s1 = 0.f, s2 = 0.f, s3 = 0.f;
  #pragma unroll 4
  for (int k4 = 0; k4 < 256; ++k4){
    float4 rv = *reinterpret_cast<const float4*>(&row[i][k4 * 4]);
    float4 a = *reinterpret_cast<const float4*>(w0 + k4 * 4);
    float4 b = *reinterpret_cast<const float4*>(w1 + k4 * 4);
    float4 c = *reinterpret_cast<const float4*>(w2 + k4 * 4);
    float4 d = *reinterpret_cast<const float4*>(w3 + k4 * 4);
    s0 = fmaf(a.x,rv.x,s0); s0 = fmaf(a.y,rv.y,s0); s0 = fmaf(a.z,rv.z,s0); s0 = fmaf(a.w,rv.w,s0);
    s1 = fmaf(b.x,rv.x,s1); s1 = fmaf(b.y,rv.y,s1); s1 = fmaf(b.z,rv.z,s1); s1 = fmaf(b.w,rv.w,s1);
    s2 = fmaf(c.x,rv.x,s2); s2 = fmaf(c.y,rv.y,s2); s2 = fmaf(c.z,rv.z,s2); s2 = fmaf(c.w,rv.w,s2);
    s3 = fmaf(d.x,rv.x,s3); s3 = fmaf(d.y,rv.y,s3); s3 = fmaf(d.z,rv.z,s3); s3 = fmaf(d.w,rv.w,s3);
  }
  int m = blk * 32 + i;
  int s = m >> 5, bb = m & 31;
  float* fp = feats + ((size_t)bb * S_LEN + s) * T_TAGS;
  float sums[4] = {s0, s1, s2, s3};
  #pragma unroll
  for (int q = 0; q < 4; ++q){
    int tt = tg + q * 8;
    if (tt < T_TAGS) fp[tt] = sums[q] + b_out[tt];
  }
}

// ---------------- phase D: CRF, one wave per batch element, register-resident ----------------
__global__ __launch_bounds__(64) void k_crf2(
    const float* __restrict__ feats, const float* __restrict__ trans,
    const int* __restrict__ tags, float* __restrict__ scores)
{
  int b = blockIdx.x;
  int l = threadIdx.x;

  float trr[T_TAGS];
  #pragma unroll
  for (int j = 0; j < T_TAGS; ++j)
    trr[j] = (l < T_TAGS) ? trans[l * T_TAGS + j] : -1e30f;

  float fv = (l == START_TAG) ? 0.f : -10000.f;
  const float* fb = feats + (size_t)b * S_LEN * T_TAGS;

  for (int s = 0; s < S_LEN; ++s){
    float feat = (l < T_TAGS) ? fb[s * T_TAGS + l] : 0.f;
    float v[T_TAGS];
    float m = -1e30f;
    #pragma unroll
    for (int j = 0; j < T_TAGS; ++j){
      float fvj = __shfl(fv, j);
      v[j] = fvj + trr[j];
      m = fmaxf(m, v[j]);
    }
    float sum = 0.f;
    #pragma unroll
    for (int j = 0; j < T_TAGS; ++j) sum += __expf(v[j] - m);
    fv = feat + m + __logf(sum);
  }

  float fin = (l < T_TAGS) ? fv + trans[STOP_TAG * T_TAGS + l] : -1e30f;
  float mm = fin;
  #pragma unroll
  for (int o = 32; o > 0; o >>= 1) mm = fmaxf(mm, __shfl_xor(mm, o));
  float e = (l < T_TAGS) ? __expf(fin - mm) : 0.f;
  #pragma unroll
  for (int o = 32; o > 0; o >>= 1) e += __shfl_xor(e, o);
  float fsc = mm + __logf(e);

  float g = 0.f;
  #pragma unroll
  for (int it = 0; it < 4; ++it){
    int s = it * 64 + l;
    int nxt = tags[s * B + b];
    int prv = s ? tags[(s - 1) * B + b] : START_TAG;
    g += trans[nxt * T_TAGS + prv] + fb[s * T_TAGS + nxt];
  }
  #pragma unroll
  for (int o = 32; o > 0; o >>= 1) g += __shfl_down(g, o);
  if (l == 0){
    int last = tags[(S_LEN - 1) * B + b];
    g += trans[STOP_TAG * T_TAGS + last];
    scores[b] = fsc - g;
  }
}

__global__ void k_final(const float* __restrict__ scores, float* __restrict__ out){
  int tid = threadIdx.x;
  float v = (tid < B) ? scores[tid] : 0.f;
  #pragma unroll
  for (int o = 32; o > 0; o >>= 1) v += __shfl_down(v, o);
  if (tid == 0) out[0] = v;
}

// ---------------- host ----------------
extern "C" void kernel_launch(void* const* d_in, const int* in_sizes, int n_in,
                              void* d_out, int out_size, void* d_ws, size_t ws_size,
                              hipStream_t stream)
{
  const int*   sent   = (const int*)d_in[0];
  const int*   tags   = (const int*)d_in[1];
  const float* emb    = (const float*)d_in[2];
  const float* w_ih_f = (const float*)d_in[3];
  const float* w_hh_f = (const float*)d_in[4];
  const float* b_ih_f = (const float*)d_in[5];
  const float* b_hh_f = (const float*)d_in[6];
  const float* w_ih_b = (const float*)d_in[7];
  const float* w_hh_b = (const float*)d_in[8];
  const float* b_ih_b = (const float*)d_in[9];
  const float* b_hh_b = (const float*)d_in[10];
  const float* w_out  = (const float*)d_in[11];
  const float* b_out  = (const float*)d_in[12];
  const float* trans  = (const float*)d_in[13];
  const float* h0     = (const float*)d_in[14];
  const float* c0     = (const float*)d_in[15];

  // ws layout (bytes)
  const size_t OFF_XW   = 0;            // bf16 [2][8192][2048] = 64 MiB
  const size_t OFF_HSEQ = 67108864;     // bf16 [2][8192][512]  = 16 MiB
  const size_t OFF_HT   = 83886080;     // bf16 [2 parity][2][32][512] = 128 KiB
  const size_t OFF_FEATS= 84017152;     // f32  [32][256][30]   = 960 KiB
  const size_t OFF_SC   = 85000192;     // f32  [32]
  const size_t OFF_BAR  = 85000320;     // u32  [64 lstm + 128 xw] = 768 B
  const size_t NEED     = 85001088;
  if (ws_size < NEED) return;

  char* ws = (char*)d_ws;
  u16*   xw     = (u16*)(ws + OFF_XW);
  u16*   hseq   = (u16*)(ws + OFF_HSEQ);
  u16*   ht     = (u16*)(ws + OFF_HT);
  float* feats  = (float*)(ws + OFF_FEATS);
  float* scores = (float*)(ws + OFF_SC);
  u32*   bar    = (u32*)(ws + OFF_BAR);

  k_init16<<<16, 256, 0, stream>>>(h0, ht, bar);

  k_mega<<<64 + NWORK, 256, 0, stream>>>(
      sent, emb, w_ih_f, w_ih_b, w_hh_f, w_hh_b,
      b_ih_f, b_hh_f, b_ih_b, b_hh_b,
      xw, ht, c0, hseq, bar);

  k_feats2<<<256, 256, 0, stream>>>(hseq, w_out, b_out, feats);
  k_crf2<<<B, 64, 0, stream>>>(feats, trans, tags, scores);
  k_final<<<1, 64, 0, stream>>>(scores, (float*)d_out);
}